// Round 5
// 296.598 us; speedup vs baseline: 1.0167x; 1.0167x over previous
//
#include <hip/hip_runtime.h>
#include <hip/hip_bf16.h>

#define HH 256
#define WW 256
#define HW (HH * WW)

typedef float f32x4 __attribute__((ext_vector_type(4)));
typedef float v2f __attribute__((ext_vector_type(2)));
typedef short bf16x8 __attribute__((ext_vector_type(8)));

__device__ __forceinline__ unsigned short f2bf(float f) {
    unsigned u = __builtin_bit_cast(unsigned, f);
    return (unsigned short)((u + 0x7FFFu + ((u >> 16) & 1u)) >> 16);
}
__device__ __forceinline__ v2f bfpair(unsigned u) {
    return (v2f){ __builtin_bit_cast(float, u << 16),
                  __builtin_bit_cast(float, u & 0xFFFF0000u) };
}
// RNE pack of two f32 -> packed bf16x2 (lo = first arg). Single v_cvt_pk_bf16_f32.
// (__hip_bfloat162 is not trivially copyable on this ROCm -> memcpy the bits.)
__device__ __forceinline__ unsigned pk_bf16(float lo, float hi) {
    __hip_bfloat162 h = __float22bfloat162_rn(make_float2(lo, hi));
    unsigned r;
    __builtin_memcpy(&r, &h, sizeof(r));
    return r;
}

// x[b][c][h][w] fp32 -> xT[b][h][w][c] bf16  (channel-last for contiguous-channel gathers)
__global__ void xt_kernel(const float* __restrict__ x, unsigned short* __restrict__ xT) {
    const int pix = blockIdx.x * 256 + threadIdx.x;       // 0..131071
    const float* xp = x + (size_t)(pix >> 16) * 64 * HW + (pix & 65535);
    unsigned short* op = xT + (size_t)pix * 64;
#pragma unroll
    for (int c8 = 0; c8 < 8; ++c8) {
        unsigned q[4];
#pragma unroll
        for (int j = 0; j < 4; ++j) {
            float a = xp[(size_t)(c8 * 8 + 2 * j) * HW];
            float b = xp[(size_t)(c8 * 8 + 2 * j + 1) * HW];
            q[j] = pk_bf16(a, b);
        }
        *(uint4*)(op + c8 * 8) = make_uint4(q[0], q[1], q[2], q[3]);
    }
}

// Weight prep:
//  WcombB[s][o][c] bf16 (s=i*9+t): sum_c2 Wfuse[o][i*64+c2] * Wd[i][c2][c][t]
//  WoffR[t][n(64 pad)][c] bf16 from Woff[n][c][t]
__global__ void wprep_kernel(const float* __restrict__ Wd,
                             const float* __restrict__ Wfuse,
                             const float* __restrict__ Woff,
                             unsigned short* __restrict__ WcombB,
                             unsigned short* __restrict__ WoffR) {
    int idx = blockIdx.x * 256 + threadIdx.x;
    if (idx < 27 * 64 * 64) {
        int c = idx & 63, o = (idx >> 6) & 63, s = idx >> 12;
        int i = s / 9, t = s - i * 9;
        const float* wf = Wfuse + o * 192 + i * 64;
        const float* wd = Wd + ((size_t)(i * 64) * 64 + c) * 9 + t;
        float acc = 0.f;
        for (int c2 = 0; c2 < 64; ++c2)
            acc = fmaf(wf[c2], wd[(size_t)c2 * 576], acc);
        WcombB[idx] = f2bf(acc);          // (s*64+o)*64 + c
    } else {
        int j = idx - 27 * 64 * 64;
        if (j < 9 * 64 * 64) {
            int c = j & 63, n = (j >> 6) & 63, t = j >> 12;
            float v = (n < 54) ? Woff[(size_t)(n * 64 + c) * 9 + t] : 0.f;
            WoffR[j] = f2bf(v);           // (t*64+n)*64 + c
        }
    }
}

// Block = 4 waves, one 64-pixel row segment. Byte-exact R5 structure (known-good
// 300.8us baseline). SINGLE delta vs R5: bf16 pack in produce/xt via one
// v_cvt_pk_bf16_f32 (RNE, bit-identical to f2bf on finite values) instead of the
// ~11-op f2bf pair. The coefw de-dup (rounds 1/3/4) is abandoned: it fails with
// build-varying absmax ~0.33-0.39 despite a clean barrier audit — unexplained,
// do not reintroduce without a mid-iteration-barrier variant tested in isolation.
__launch_bounds__(256, 4)
__global__ void mspadc_main(const unsigned short* __restrict__ xT,
                            const unsigned short* __restrict__ WoffR,
                            const float* __restrict__ boff,
                            const unsigned short* __restrict__ WcombB,
                            float* __restrict__ out) {
    __shared__ float offL[64 * 65];                          // [n][p] pitch 65
    __shared__ __align__(16) unsigned short Sb[2][64 * 66];  // [p][c] pitch 66

    const int tid = threadIdx.x, lane = tid & 63, wv = tid >> 6;
    const int l15 = lane & 15, lq = lane >> 4;

    const unsigned u = blockIdx.x;
    const int xcd = u & 7, v = u >> 3;                    // XCD-band swizzle
    const int row = xcd * 64 + (v >> 2);                  // 0..511
    const int b = row >> 8, h = row & 255;
    const int w0 = (v & 3) << 6;

    const unsigned short* xTb = xT + (size_t)b * HW * 64;

    f32x4 acc[4];
#pragma unroll
    for (int nt = 0; nt < 4; ++nt) acc[nt] = (f32x4){0.f, 0.f, 0.f, 0.f};

    // ---------------- Phase 1: offset conv GEMM ----------------
#pragma unroll
    for (int t = 0; t < 9; ++t) {
        const int hh = h + t / 3 - 1;
        const bool hv = (hh >= 0) && (hh < HH);
#pragma unroll
        for (int kk = 0; kk < 2; ++kk) {
            bf16x8 a = *(const bf16x8*)(WoffR + (size_t)((t * 64 + 16 * wv + l15) * 64 + kk * 32 + lq * 8));
#pragma unroll
            for (int nt = 0; nt < 4; ++nt) {
                const int ww = w0 + nt * 16 + l15 + (t % 3) - 1;
                bf16x8 bf_ = {0, 0, 0, 0, 0, 0, 0, 0};
                if (hv && ww >= 0 && ww < WW)
                    bf_ = *(const bf16x8*)(xTb + (size_t)(hh * WW + ww) * 64 + kk * 32 + lq * 8);
                acc[nt] = __builtin_amdgcn_mfma_f32_16x16x32_bf16(a, bf_, acc[nt], 0, 0, 0);
            }
        }
    }
#pragma unroll
    for (int r = 0; r < 4; ++r) {
        const int nch = 16 * wv + lq * 4 + r;
        const float bo = (nch < 54) ? boff[nch] : 0.f;
#pragma unroll
        for (int nt = 0; nt < 4; ++nt)
            offL[nch * 65 + nt * 16 + l15] = acc[nt][r] + bo;
    }
    __syncthreads();

#pragma unroll
    for (int nt = 0; nt < 4; ++nt) acc[nt] = (f32x4){0.f, 0.f, 0.f, 0.f};

    // ---------------- Phase 2: gather + main GEMM ----------------
    const int c8 = tid & 7;        // channel chunk (8 ch = 16B)
    const int psub = tid >> 3;     // pixel 0..31 (+32 second half)

    auto produce = [&](int s, int buf) {
        const int i = s / 9, t = s - i * 9;
        const int d = 1 << i;
#pragma unroll
        for (int r8 = 0; r8 < 2; ++r8) {
            const int p = 32 * r8 + psub;
            const float dy = offL[(i * 18 + 2 * t) * 65 + p];
            const float dx = offL[(i * 18 + 2 * t + 1) * 65 + p];
            const float ys = (float)(h + (t / 3 - 1) * d) + dy;
            const float xs = (float)(w0 + p + (t % 3 - 1) * d) + dx;
            const float y0f = floorf(ys), x0f = floorf(xs);
            const float wy1 = ys - y0f, wx1 = xs - x0f;
            const float wy0 = 1.f - wy1, wx0 = 1.f - wx1;
            const float vy0 = (y0f >= 0.f && y0f <= 255.f) ? 1.f : 0.f;
            const float vy1 = (y0f >= -1.f && y0f <= 254.f) ? 1.f : 0.f;
            const float vx0 = (x0f >= 0.f && x0f <= 255.f) ? 1.f : 0.f;
            const float vx1 = (x0f >= -1.f && x0f <= 254.f) ? 1.f : 0.f;
            const float c00 = wy0 * wx0 * vy0 * vx0;
            const float c01 = wy0 * wx1 * vy0 * vx1;
            const float c10 = wy1 * wx0 * vy1 * vx0;
            const float c11 = wy1 * wx1 * vy1 * vx1;
            const int y0 = (int)fminf(fmaxf(y0f, 0.f), 255.f);
            const int x0 = (int)fminf(fmaxf(x0f, 0.f), 255.f);
            const int oxs = (((int)fminf(fmaxf(x0f + 1.f, 0.f), 255.f)) - x0) * 64;
            const int oyW = (((int)fminf(fmaxf(y0f + 1.f, 0.f), 255.f)) - y0) * WW * 64;
            const unsigned short* pc = xTb + (size_t)(y0 * WW + x0) * 64 + c8 * 8;
            const uint4 u00 = *(const uint4*)(pc);
            const uint4 u01 = *(const uint4*)(pc + oxs);
            const uint4 u10 = *(const uint4*)(pc + oyW);
            const uint4 u11 = *(const uint4*)(pc + oyW + oxs);
            const unsigned a00[4] = {u00.x, u00.y, u00.z, u00.w};
            const unsigned a01[4] = {u01.x, u01.y, u01.z, u01.w};
            const unsigned a10[4] = {u10.x, u10.y, u10.z, u10.w};
            const unsigned a11[4] = {u11.x, u11.y, u11.z, u11.w};
            const v2f c00v = {c00, c00}, c01v = {c01, c01};
            const v2f c10v = {c10, c10}, c11v = {c11, c11};
            unsigned q[4];
#pragma unroll
            for (int j = 0; j < 4; ++j) {
                v2f s2 = bfpair(a00[j]) * c00v;
                s2 = __builtin_elementwise_fma(bfpair(a01[j]), c01v, s2);
                s2 = __builtin_elementwise_fma(bfpair(a10[j]), c10v, s2);
                s2 = __builtin_elementwise_fma(bfpair(a11[j]), c11v, s2);
                q[j] = pk_bf16(s2.x, s2.y);
            }
            *(uint4*)(&Sb[buf][p * 66 + c8 * 8]) = make_uint4(q[0], q[1], q[2], q[3]);
        }
    };

    auto consume = [&](int s, int buf) {
#pragma unroll
        for (int kk = 0; kk < 2; ++kk) {
            bf16x8 a = *(const bf16x8*)(WcombB + (size_t)((s * 64 + 16 * wv + l15) * 64 + kk * 32 + lq * 8));
#pragma unroll
            for (int nt = 0; nt < 4; ++nt) {
                bf16x8 bb = *(const bf16x8*)(&Sb[buf][(nt * 16 + l15) * 66 + kk * 32 + lq * 8]);
                acc[nt] = __builtin_amdgcn_mfma_f32_16x16x32_bf16(a, bb, acc[nt], 0, 0, 0);
            }
        }
    };

    produce(0, 0);
    __syncthreads();
    for (int s = 0; s < 27; ++s) {
        if (s < 26) produce(s + 1, (s + 1) & 1);
        consume(s, s & 1);
        __syncthreads();
    }

    // ---------------- Epilogue ----------------
    float* ob = out + (size_t)b * 64 * HW + h * WW + w0;
#pragma unroll
    for (int nt = 0; nt < 4; ++nt)
#pragma unroll
        for (int r = 0; r < 4; ++r) {
            const int o = 16 * wv + lq * 4 + r;
            ob[(size_t)o * HW + nt * 16 + l15] = acc[nt][r];
        }
}

extern "C" void kernel_launch(void* const* d_in, const int* in_sizes, int n_in,
                              void* d_out, int out_size, void* d_ws, size_t ws_size,
                              hipStream_t stream) {
    const float* x     = (const float*)d_in[0];
    const float* Woff  = (const float*)d_in[1];
    const float* boff  = (const float*)d_in[2];
    const float* Wd    = (const float*)d_in[3];
    const float* Wfuse = (const float*)d_in[4];
    float* out = (float*)d_out;

    unsigned short* WcombB = (unsigned short*)d_ws;        // 27*64*64*2   = 221184 B
    unsigned short* WoffR  = WcombB + 27 * 64 * 64;        // 9*64*64*2    =  73728 B
    unsigned short* xT     = WoffR + 9 * 64 * 64;          // 2*HW*64*2    = 16.78 MB

    xt_kernel<<<512, 256, 0, stream>>>(x, xT);
    wprep_kernel<<<576, 256, 0, stream>>>(Wd, Wfuse, Woff, WcombB, WoffR);
    mspadc_main<<<2048, 256, 0, stream>>>(xT, WoffR, boff, WcombB, out);
}

// Round 7
// 290.590 us; speedup vs baseline: 1.0377x; 1.0207x over previous
//
#include <hip/hip_runtime.h>
#include <hip/hip_bf16.h>

#define HH 256
#define WW 256
#define HW (HH * WW)

typedef float f32x4 __attribute__((ext_vector_type(4)));
typedef float v2f __attribute__((ext_vector_type(2)));
typedef short bf16x8 __attribute__((ext_vector_type(8)));

__device__ __forceinline__ unsigned short f2bf(float f) {
    unsigned u = __builtin_bit_cast(unsigned, f);
    return (unsigned short)((u + 0x7FFFu + ((u >> 16) & 1u)) >> 16);
}
__device__ __forceinline__ v2f bfpair(unsigned u) {
    return (v2f){ __builtin_bit_cast(float, u << 16),
                  __builtin_bit_cast(float, u & 0xFFFF0000u) };
}
// RNE pack of two f32 -> packed bf16x2 (lo = first arg). Single v_cvt_pk_bf16_f32.
// (__hip_bfloat162 is not trivially copyable on this ROCm -> memcpy the bits.)
__device__ __forceinline__ unsigned pk_bf16(float lo, float hi) {
    __hip_bfloat162 h = __float22bfloat162_rn(make_float2(lo, hi));
    unsigned r;
    __builtin_memcpy(&r, &h, sizeof(r));
    return r;
}

// x[b][c][h][w] fp32 -> xT[b][h][w][c] bf16  (channel-last for contiguous-channel gathers)
__global__ void xt_kernel(const float* __restrict__ x, unsigned short* __restrict__ xT) {
    const int pix = blockIdx.x * 256 + threadIdx.x;       // 0..131071
    const float* xp = x + (size_t)(pix >> 16) * 64 * HW + (pix & 65535);
    unsigned short* op = xT + (size_t)pix * 64;
#pragma unroll
    for (int c8 = 0; c8 < 8; ++c8) {
        unsigned q[4];
#pragma unroll
        for (int j = 0; j < 4; ++j) {
            float a = xp[(size_t)(c8 * 8 + 2 * j) * HW];
            float b = xp[(size_t)(c8 * 8 + 2 * j + 1) * HW];
            q[j] = pk_bf16(a, b);
        }
        *(uint4*)(op + c8 * 8) = make_uint4(q[0], q[1], q[2], q[3]);
    }
}

// Weight prep:
//  WcombB[s][o][c] bf16 (s=i*9+t): sum_c2 Wfuse[o][i*64+c2] * Wd[i][c2][c][t]
//  WoffR[t][n(64 pad)][c] bf16 from Woff[n][c][t]
__global__ void wprep_kernel(const float* __restrict__ Wd,
                             const float* __restrict__ Wfuse,
                             const float* __restrict__ Woff,
                             unsigned short* __restrict__ WcombB,
                             unsigned short* __restrict__ WoffR) {
    int idx = blockIdx.x * 256 + threadIdx.x;
    if (idx < 27 * 64 * 64) {
        int c = idx & 63, o = (idx >> 6) & 63, s = idx >> 12;
        int i = s / 9, t = s - i * 9;
        const float* wf = Wfuse + o * 192 + i * 64;
        const float* wd = Wd + ((size_t)(i * 64) * 64 + c) * 9 + t;
        float acc = 0.f;
        for (int c2 = 0; c2 < 64; ++c2)
            acc = fmaf(wf[c2], wd[(size_t)c2 * 576], acc);
        WcombB[idx] = f2bf(acc);          // (s*64+o)*64 + c
    } else {
        int j = idx - 27 * 64 * 64;
        if (j < 9 * 64 * 64) {
            int c = j & 63, n = (j >> 6) & 63, t = j >> 12;
            float v = (n < 54) ? Woff[(size_t)(n * 64 + c) * 9 + t] : 0.f;
            WoffR[j] = f2bf(v);           // (t*64+n)*64 + c
        }
    }
}

// Block = 4 waves, one 64-pixel row segment. R5 structure + banked pack intrinsic.
// SINGLE delta this round: produce's thread mapping is 4 threads/pixel x 16 ch
// (c16 = tid&3, px = tid>>2, no r8 loop) instead of 8 threads/pixel x 8 ch x 2
// pixels — the per-(pixel,slice) coefficient block runs once per thread (was 2x)
// and is duplicated 4x per pixel (was 8x). Formulas, FP order, Sb layout,
// consume, phase 1, and barriers are byte-identical to the verified kernel.
// (The cross-wave coefw LDS pipeline from rounds 1/3/4 is abandoned: fails with
// build-varying absmax ~0.33-0.39 despite repeated clean audits.)
__launch_bounds__(256, 4)
__global__ void mspadc_main(const unsigned short* __restrict__ xT,
                            const unsigned short* __restrict__ WoffR,
                            const float* __restrict__ boff,
                            const unsigned short* __restrict__ WcombB,
                            float* __restrict__ out) {
    __shared__ float offL[64 * 65];                          // [n][p] pitch 65
    __shared__ __align__(16) unsigned short Sb[2][64 * 66];  // [p][c] pitch 66

    const int tid = threadIdx.x, lane = tid & 63, wv = tid >> 6;
    const int l15 = lane & 15, lq = lane >> 4;

    const unsigned u = blockIdx.x;
    const int xcd = u & 7, v = u >> 3;                    // XCD-band swizzle
    const int row = xcd * 64 + (v >> 2);                  // 0..511
    const int b = row >> 8, h = row & 255;
    const int w0 = (v & 3) << 6;

    const unsigned short* xTb = xT + (size_t)b * HW * 64;

    f32x4 acc[4];
#pragma unroll
    for (int nt = 0; nt < 4; ++nt) acc[nt] = (f32x4){0.f, 0.f, 0.f, 0.f};

    // ---------------- Phase 1: offset conv GEMM ----------------
#pragma unroll
    for (int t = 0; t < 9; ++t) {
        const int hh = h + t / 3 - 1;
        const bool hv = (hh >= 0) && (hh < HH);
#pragma unroll
        for (int kk = 0; kk < 2; ++kk) {
            bf16x8 a = *(const bf16x8*)(WoffR + (size_t)((t * 64 + 16 * wv + l15) * 64 + kk * 32 + lq * 8));
#pragma unroll
            for (int nt = 0; nt < 4; ++nt) {
                const int ww = w0 + nt * 16 + l15 + (t % 3) - 1;
                bf16x8 bf_ = {0, 0, 0, 0, 0, 0, 0, 0};
                if (hv && ww >= 0 && ww < WW)
                    bf_ = *(const bf16x8*)(xTb + (size_t)(hh * WW + ww) * 64 + kk * 32 + lq * 8);
                acc[nt] = __builtin_amdgcn_mfma_f32_16x16x32_bf16(a, bf_, acc[nt], 0, 0, 0);
            }
        }
    }
#pragma unroll
    for (int r = 0; r < 4; ++r) {
        const int nch = 16 * wv + lq * 4 + r;
        const float bo = (nch < 54) ? boff[nch] : 0.f;
#pragma unroll
        for (int nt = 0; nt < 4; ++nt)
            offL[nch * 65 + nt * 16 + l15] = acc[nt][r] + bo;
    }
    __syncthreads();

#pragma unroll
    for (int nt = 0; nt < 4; ++nt) acc[nt] = (f32x4){0.f, 0.f, 0.f, 0.f};

    // ---------------- Phase 2: gather + main GEMM ----------------
    const int c16 = tid & 3;       // 16-channel chunk (32B = two uint4)
    const int px  = tid >> 2;      // pixel 0..63 (one per thread)

    auto produce = [&](int s, int buf) {
        const int i = s / 9, t = s - i * 9;
        const int d = 1 << i;
        const int p = px;
        const float dy = offL[(i * 18 + 2 * t) * 65 + p];
        const float dx = offL[(i * 18 + 2 * t + 1) * 65 + p];
        const float ys = (float)(h + (t / 3 - 1) * d) + dy;
        const float xs = (float)(w0 + p + (t % 3 - 1) * d) + dx;
        const float y0f = floorf(ys), x0f = floorf(xs);
        const float wy1 = ys - y0f, wx1 = xs - x0f;
        const float wy0 = 1.f - wy1, wx0 = 1.f - wx1;
        const float vy0 = (y0f >= 0.f && y0f <= 255.f) ? 1.f : 0.f;
        const float vy1 = (y0f >= -1.f && y0f <= 254.f) ? 1.f : 0.f;
        const float vx0 = (x0f >= 0.f && x0f <= 255.f) ? 1.f : 0.f;
        const float vx1 = (x0f >= -1.f && x0f <= 254.f) ? 1.f : 0.f;
        const float c00 = wy0 * wx0 * vy0 * vx0;
        const float c01 = wy0 * wx1 * vy0 * vx1;
        const float c10 = wy1 * wx0 * vy1 * vx0;
        const float c11 = wy1 * wx1 * vy1 * vx1;
        const int y0 = (int)fminf(fmaxf(y0f, 0.f), 255.f);
        const int x0 = (int)fminf(fmaxf(x0f, 0.f), 255.f);
        const int oxs = (((int)fminf(fmaxf(x0f + 1.f, 0.f), 255.f)) - x0) * 64;
        const int oyW = (((int)fminf(fmaxf(y0f + 1.f, 0.f), 255.f)) - y0) * WW * 64;
        const unsigned short* pc = xTb + (size_t)(y0 * WW + x0) * 64 + c16 * 16;
        const uint4 u00a = *(const uint4*)(pc);
        const uint4 u00b = *(const uint4*)(pc + 8);
        const uint4 u01a = *(const uint4*)(pc + oxs);
        const uint4 u01b = *(const uint4*)(pc + oxs + 8);
        const uint4 u10a = *(const uint4*)(pc + oyW);
        const uint4 u10b = *(const uint4*)(pc + oyW + 8);
        const uint4 u11a = *(const uint4*)(pc + oyW + oxs);
        const uint4 u11b = *(const uint4*)(pc + oyW + oxs + 8);
        const unsigned a00[8] = {u00a.x, u00a.y, u00a.z, u00a.w, u00b.x, u00b.y, u00b.z, u00b.w};
        const unsigned a01[8] = {u01a.x, u01a.y, u01a.z, u01a.w, u01b.x, u01b.y, u01b.z, u01b.w};
        const unsigned a10[8] = {u10a.x, u10a.y, u10a.z, u10a.w, u10b.x, u10b.y, u10b.z, u10b.w};
        const unsigned a11[8] = {u11a.x, u11a.y, u11a.z, u11a.w, u11b.x, u11b.y, u11b.z, u11b.w};
        const v2f c00v = {c00, c00}, c01v = {c01, c01};
        const v2f c10v = {c10, c10}, c11v = {c11, c11};
        unsigned q[8];
#pragma unroll
        for (int j = 0; j < 8; ++j) {
            v2f s2 = bfpair(a00[j]) * c00v;
            s2 = __builtin_elementwise_fma(bfpair(a01[j]), c01v, s2);
            s2 = __builtin_elementwise_fma(bfpair(a10[j]), c10v, s2);
            s2 = __builtin_elementwise_fma(bfpair(a11[j]), c11v, s2);
            q[j] = pk_bf16(s2.x, s2.y);
        }
        *(uint4*)(&Sb[buf][p * 66 + c16 * 16]) = make_uint4(q[0], q[1], q[2], q[3]);
        *(uint4*)(&Sb[buf][p * 66 + c16 * 16 + 8]) = make_uint4(q[4], q[5], q[6], q[7]);
    };

    auto consume = [&](int s, int buf) {
#pragma unroll
        for (int kk = 0; kk < 2; ++kk) {
            bf16x8 a = *(const bf16x8*)(WcombB + (size_t)((s * 64 + 16 * wv + l15) * 64 + kk * 32 + lq * 8));
#pragma unroll
            for (int nt = 0; nt < 4; ++nt) {
                bf16x8 bb = *(const bf16x8*)(&Sb[buf][(nt * 16 + l15) * 66 + kk * 32 + lq * 8]);
                acc[nt] = __builtin_amdgcn_mfma_f32_16x16x32_bf16(a, bb, acc[nt], 0, 0, 0);
            }
        }
    };

    produce(0, 0);
    __syncthreads();
    for (int s = 0; s < 27; ++s) {
        if (s < 26) produce(s + 1, (s + 1) & 1);
        consume(s, s & 1);
        __syncthreads();
    }

    // ---------------- Epilogue ----------------
    float* ob = out + (size_t)b * 64 * HW + h * WW + w0;
#pragma unroll
    for (int nt = 0; nt < 4; ++nt)
#pragma unroll
        for (int r = 0; r < 4; ++r) {
            const int o = 16 * wv + lq * 4 + r;
            ob[(size_t)o * HW + nt * 16 + l15] = acc[nt][r];
        }
}

extern "C" void kernel_launch(void* const* d_in, const int* in_sizes, int n_in,
                              void* d_out, int out_size, void* d_ws, size_t ws_size,
                              hipStream_t stream) {
    const float* x     = (const float*)d_in[0];
    const float* Woff  = (const float*)d_in[1];
    const float* boff  = (const float*)d_in[2];
    const float* Wd    = (const float*)d_in[3];
    const float* Wfuse = (const float*)d_in[4];
    float* out = (float*)d_out;

    unsigned short* WcombB = (unsigned short*)d_ws;        // 27*64*64*2   = 221184 B
    unsigned short* WoffR  = WcombB + 27 * 64 * 64;        // 9*64*64*2    =  73728 B
    unsigned short* xT     = WoffR + 9 * 64 * 64;          // 2*HW*64*2    = 16.78 MB

    xt_kernel<<<512, 256, 0, stream>>>(x, xT);
    wprep_kernel<<<576, 256, 0, stream>>>(Wd, Wfuse, Woff, WcombB, WoffR);
    mspadc_main<<<2048, 256, 0, stream>>>(xT, WoffR, boff, WcombB, out);
}